// Round 11
// baseline (175.811 us; speedup 1.0000x reference)
//
#include <hip/hip_runtime.h>
#include <cstdint>

#define N 4096
#define D 1024
#define KC_COUNT (D / 32)    // 32 k-chunks of 32
#define TB (N / 128)         // 32 tile rows/cols of 128 (4096 = 32*128, no pad)
#define NBLK (TB * (TB + 1) / 2)   // 528 upper-triangular 128x128 tiles

typedef _Float16 f16;
typedef __attribute__((ext_vector_type(4))) _Float16 f16x4;
typedef __attribute__((ext_vector_type(8))) _Float16 f16x8;
typedef __attribute__((ext_vector_type(4))) float f32x4;

// Monotone map fp32 -> u32 so unsigned compare == float compare (ascending).
__device__ __forceinline__ unsigned int orderable(float f) {
    unsigned int b = __float_as_uint(f);
    return (b & 0x80000000u) ? ~b : (b | 0x80000000u);
}

__device__ __forceinline__ void async_copy16(const f16* g, f16* l) {
    __builtin_amdgcn_global_load_lds(
        (const __attribute__((address_space(1))) uint32_t*)(const void*)g,
        (__attribute__((address_space(3))) uint32_t*)(void*)l,
        16 /*bytes*/, 0 /*offset*/, 0 /*aux*/);
}

// Split fp32 X into f16 hi/lo planes pre-swizzled into MFMA fragment order:
// chunk (rg, kc, hl) holds 512 f16 ordered by lane=(q<<4)|m, elem=k&7, where
// row = rg*16+m, k = kc*32+q*8+elem. 1024 blocks: rg 0..255 x kquarter 0..3.
// LDS stride 280 f16 = 140 dw == 12 mod 32: phase-2 b128 reads 2-way (free).
#define KSPAN 256
#define SS_STRIDE (KSPAN + 24)   // 280 f16 = 560 B
__global__ __launch_bounds__(256) void split_swizzle(
    const float* __restrict__ X, f16* __restrict__ Xsw,
    unsigned long long* __restrict__ keys)
{
    __shared__ f16 Hs[16 * SS_STRIDE];
    __shared__ f16 Ls[16 * SS_STRIDE];
    const int tid = threadIdx.x;
    const int bid = blockIdx.x;
    const int rg = bid >> 2, kq = bid & 3;
    if (bid < 32) keys[bid * 256 + tid] = 0xFFFFFFFFFFFFFFFFull;

    // Phase 1: coalesced fp32 read -> split -> LDS row-major.
#pragma unroll
    for (int i = 0; i < 4; ++i) {
        const int idx4 = i * 256 + tid;        // 1024 float4 slots
        const int row = idx4 >> 6, c4 = idx4 & 63;
        const float4 v = *(const float4*)(X + (size_t)(rg * 16 + row) * D + kq * KSPAN + c4 * 4);
        const float xs[4] = {v.x, v.y, v.z, v.w};
        f16x4 h, l;
#pragma unroll
        for (int e = 0; e < 4; ++e) {
            f16 hh = (f16)xs[e];
            h[e] = hh;
            l[e] = (f16)(xs[e] - (float)hh);
        }
        *(f16x4*)(Hs + row * SS_STRIDE + c4 * 4) = h;
        *(f16x4*)(Ls + row * SS_STRIDE + c4 * 4) = l;
    }
    __syncthreads();

    // Phase 2: swizzled b128 LDS reads -> coalesced global stores.
#pragma unroll
    for (int hl = 0; hl < 2; ++hl) {
        const f16* lds = hl ? Ls : Hs;
#pragma unroll
        for (int i = 0; i < 2; ++i) {
            const int o = i * 256 + tid;       // 512 uint4 slots
            const int kcl = o >> 6, lo_ = o & 63;
            const int q = lo_ >> 4, m = lo_ & 15;
            const uint4 v = *(const uint4*)(lds + m * SS_STRIDE + kcl * 32 + q * 8);
            const int kc = kq * 8 + kcl;
            *(uint4*)(Xsw + (((size_t)rg * KC_COUNT + kc) * 2 + hl) * 512 + lo_ * 8) = v;
        }
    }
}

// 128x128 upper-triangular tile of dist = X @ X^T, EIGHT waves (2x4 grid of
// 64x32 regions), f16-split MFMA (hi*hi + hi*lo + lo*hi), single-buffer
// 2-barrier LDS loop. 528 blocks x 8 waves = 16.5 waves/CU at 2 blocks/CU:
// R3's wave pressure + 128-tile staging ratio + triangle work savings.
__global__ __launch_bounds__(512, 4) void gemm_argmin_sym(
    const f16* __restrict__ Xsw, const int* __restrict__ labels,
    unsigned long long* __restrict__ keys_ap,
    unsigned long long* __restrict__ keys_an)
{
    __shared__ f16 As[8 * 2 * 512];   // [rgLocal(8)][hl(2)][lane(64)][8] = 16 KB
    __shared__ f16 Bs[8 * 2 * 512];   // 16 KB

    // Decode linear block id -> (ti, tj) with ti <= tj over TB=32.
    int r = blockIdx.x, ti = 0;
    while (r >= TB - ti) { r -= TB - ti; ++ti; }
    const int tj = ti + r;

    const int tid = threadIdx.x;
    const int lane = tid & 63;
    const int w = tid >> 6;            // wave 0..7
    const int wr = w >> 2, wc = w & 3; // 2x4 wave grid, 64x32 region each
    const int rowBase = ti * 128, colBase = tj * 128;

    f32x4 acc[4][2];
#pragma unroll
    for (int mi = 0; mi < 4; ++mi)
#pragma unroll
        for (int ni = 0; ni < 2; ++ni) acc[mi][ni] = (f32x4){0.f, 0.f, 0.f, 0.f};

    // Wave w stages chunks c = w*4 .. w*4+3 (32 total: A/B x 8rg x hi/lo).
    const f16* g[4];
    f16* lp[4];
#pragma unroll
    for (int j = 0; j < 4; ++j) {
        int c = w * 4 + j;
        int isB = c >> 4, rem = c & 15, rgL = rem >> 1, hl = rem & 1;
        int rgG = (isB ? tj : ti) * 8 + rgL;
        g[j] = Xsw + ((((size_t)rgG * KC_COUNT) * 2 + hl) * 64 + lane) * 8;  // kc=0
        lp[j] = (isB ? Bs : As) + (rgL * 2 + hl) * 512;  // wave-uniform base
    }

    for (int kc = 0; kc < KC_COUNT; ++kc) {
#pragma unroll
        for (int j = 0; j < 4; ++j)
            async_copy16(g[j] + (size_t)kc * 1024, lp[j]);
        __syncthreads();   // drain: tile ready

        f16x8 ah[4], al[4], bh[2], bl[2];
#pragma unroll
        for (int t2 = 0; t2 < 4; ++t2) {
            int rgA = wr * 4 + t2;
            ah[t2] = *(const f16x8*)(As + (rgA * 2 + 0) * 512 + lane * 8);
            al[t2] = *(const f16x8*)(As + (rgA * 2 + 1) * 512 + lane * 8);
        }
#pragma unroll
        for (int t2 = 0; t2 < 2; ++t2) {
            int rgB = wc * 2 + t2;
            bh[t2] = *(const f16x8*)(Bs + (rgB * 2 + 0) * 512 + lane * 8);
            bl[t2] = *(const f16x8*)(Bs + (rgB * 2 + 1) * 512 + lane * 8);
        }
#pragma unroll
        for (int mi = 0; mi < 4; ++mi)
#pragma unroll
            for (int ni = 0; ni < 2; ++ni) {
                acc[mi][ni] = __builtin_amdgcn_mfma_f32_16x16x32_f16(
                    ah[mi], bh[ni], acc[mi][ni], 0, 0, 0);
                acc[mi][ni] = __builtin_amdgcn_mfma_f32_16x16x32_f16(
                    ah[mi], bl[ni], acc[mi][ni], 0, 0, 0);
                acc[mi][ni] = __builtin_amdgcn_mfma_f32_16x16x32_f16(
                    al[mi], bh[ni], acc[mi][ni], 0, 0, 0);
            }
        __syncthreads();   // all reads done before next stage overwrites
    }

    // Epilogue. C/D layout (16x16): col = lane&15, row = (lane>>4)*4 + reg.
    const int g16 = lane >> 4, c16 = lane & 15;

    int ljv[2], liv[4][4];
#pragma unroll
    for (int ni = 0; ni < 2; ++ni)
        ljv[ni] = labels[colBase + wc * 32 + ni * 16 + c16];
#pragma unroll
    for (int mi = 0; mi < 4; ++mi)
#pragma unroll
        for (int reg = 0; reg < 4; ++reg)
            liv[mi][reg] = labels[rowBase + wr * 64 + mi * 16 + g16 * 4 + reg];

    // Pass 1: row-side argmin (rows of ti-range over cols of tj-range).
#pragma unroll
    for (int mi = 0; mi < 4; ++mi) {
#pragma unroll
        for (int reg = 0; reg < 4; ++reg) {
            const int i = rowBase + wr * 64 + mi * 16 + g16 * 4 + reg;
            const int li = liv[mi][reg];
            float bestAp = __builtin_huge_valf(); int jAp = 0;
            float bestAn = __builtin_huge_valf(); int jAn = 0;
#pragma unroll
            for (int ni = 0; ni < 2; ++ni) {
                const int jcol = colBase + wc * 32 + ni * 16 + c16;
                const float v = acc[mi][ni][reg];
                const bool same = (li == ljv[ni]);
                const float vap = (same && (i != jcol)) ? v : v + 2.0f;
                const float van = (!same) ? v : v + 2.0f;
                if (vap < bestAp) { bestAp = vap; jAp = jcol; }
                if (van < bestAn) { bestAn = van; jAn = jcol; }
            }
            unsigned long long kap =
                ((unsigned long long)orderable(bestAp) << 32) | (unsigned)jAp;
            unsigned long long kan =
                ((unsigned long long)orderable(bestAn) << 32) | (unsigned)jAn;
#pragma unroll
            for (int off = 1; off < 16; off <<= 1) {
                unsigned long long o = __shfl_xor(kap, off); kap = o < kap ? o : kap;
                o = __shfl_xor(kan, off); kan = o < kan ? o : kan;
            }
            if (c16 == 0) {
                atomicMin(&keys_ap[i], kap);
                atomicMin(&keys_an[i], kan);
            }
        }
    }

    // Pass 2 (off-diagonal only): column-side argmin via symmetry.
    if (ti != tj) {
#pragma unroll
        for (int ni = 0; ni < 2; ++ni) {
            const int j = colBase + wc * 32 + ni * 16 + c16;
            const int lj = ljv[ni];
            float bestAp = __builtin_huge_valf(); int iAp = 0;
            float bestAn = __builtin_huge_valf(); int iAn = 0;
#pragma unroll
            for (int mi = 0; mi < 4; ++mi)
#pragma unroll
                for (int reg = 0; reg < 4; ++reg) {
                    const int i = rowBase + wr * 64 + mi * 16 + g16 * 4 + reg;
                    const float v = acc[mi][ni][reg];
                    const bool same = (liv[mi][reg] == lj);
                    const float vap = same ? v : v + 2.0f;   // i != j off-diag
                    const float van = (!same) ? v : v + 2.0f;
                    if (vap < bestAp) { bestAp = vap; iAp = i; }
                    if (van < bestAn) { bestAn = van; iAn = i; }
                }
            unsigned long long kap =
                ((unsigned long long)orderable(bestAp) << 32) | (unsigned)iAp;
            unsigned long long kan =
                ((unsigned long long)orderable(bestAn) << 32) | (unsigned)iAn;
            // Reduce over g16 (lane bits 4,5): lanes sharing c16 share j.
#pragma unroll
            for (int off = 16; off < 64; off <<= 1) {
                unsigned long long o = __shfl_xor(kap, off); kap = o < kap ? o : kap;
                o = __shfl_xor(kan, off); kan = o < kan ? o : kan;
            }
            if (g16 == 0) {
                atomicMin(&keys_ap[j], kap);
                atomicMin(&keys_an[j], kan);
            }
        }
    }
}

__global__ void gather_rows(const float* __restrict__ A,
                            const unsigned long long* __restrict__ keys_ap,
                            const unsigned long long* __restrict__ keys_an,
                            float* __restrict__ out)
{
    const int row = blockIdx.x;
    const int t = threadIdx.x;
    const int ja = (int)(keys_ap[row] & 0xFFFFFFFFull);
    const int jn = (int)(keys_an[row] & 0xFFFFFFFFull);
    const float4* Av = (const float4*)A;
    float4* Ov = (float4*)out;
    Ov[(size_t)row * (D / 4) + t]       = Av[(size_t)ja * (D / 4) + t];
    Ov[(size_t)(N + row) * (D / 4) + t] = Av[(size_t)jn * (D / 4) + t];
}

extern "C" void kernel_launch(void* const* d_in, const int* in_sizes, int n_in,
                              void* d_out, int out_size, void* d_ws, size_t ws_size,
                              hipStream_t stream) {
    const float* A = (const float*)d_in[0];
    const int* labels = (const int*)d_in[1];  // integer inputs arrive as int32
    float* out = (float*)d_out;

    unsigned long long* keys = (unsigned long long*)d_ws;          // 64 KB
    f16* Xsw = (f16*)((char*)d_ws + 65536);                        // 16 MB hi+lo

    split_swizzle<<<(N / 16) * 4, 256, 0, stream>>>(A, Xsw, keys);
    gemm_argmin_sym<<<NBLK, 512, 0, stream>>>(Xsw, labels, keys, keys + N);
    gather_rows<<<N, 256, 0, stream>>>(A, keys, keys + N, out);
}